// Round 10
// baseline (75.682 us; speedup 1.0000x reference)
//
#include <hip/hip_runtime.h>
#include <math.h>

#define KK 8
#define LOG2E   1.4426950408889634f
#define HL2E    0.7213475204444817f   // 0.5 * log2(e)
#define LN2     0.6931471805599453f
#define C2CONST 5.3029936094f         // 2 * log2(2*pi)
#define L2CLIP8 -26.575424759f        // log2(1e-8)

// ws: M*K param blocks of 16 floats:
//   mu0..3 | w00,w10,w11,w20 | w21,w22,w30,w31 | w32,w33,c2,pad

// ---------------------------------------------------------------------------
// Kernel A: one thread per (m,k). softmax(pi), W=L^{-1}, log2-domain c2 ->
// ws; z prefix cols (mu, ln|Ldiag| clip 1e-6, pi) -> d_out.
// ---------------------------------------------------------------------------
__global__ __launch_bounds__(256) void gmm_setup(const float* __restrict__ phi,
                                                 float* __restrict__ ws,
                                                 float* __restrict__ z) {
    const int tid = blockIdx.x * 256 + threadIdx.x;   // 0..4095
    const int m = tid >> 3, k = tid & 7;
    const float* row = phi + m * 120;

    float mx = row[0];
    #pragma unroll
    for (int j = 1; j < KK; ++j) mx = fmaxf(mx, row[j]);
    float s = 0.f;
    #pragma unroll
    for (int j = 0; j < KK; ++j)
        s += __builtin_amdgcn_exp2f((row[j] - mx) * LOG2E);
    float l2s = __builtin_amdgcn_logf(s);             // log2(s)
    float pik = __builtin_amdgcn_exp2f((row[k] - mx) * LOG2E) *
                __builtin_amdgcn_rcpf(s);
    float l2pi = fmaxf((row[k] - mx) * LOG2E - l2s, L2CLIP8);  // log2(clip pi)

    const float* muk = row + 8 + k * 4;
    const float* Lv  = row + 40 + k * 10;
    // tril(D=4) order: l00,l10,l11,l20,l21,l22,l30,l31,l32,l33
    float l00 = Lv[0], l10 = Lv[1], l11 = Lv[2], l20 = Lv[3], l21 = Lv[4],
          l22 = Lv[5], l30 = Lv[6], l31 = Lv[7], l32 = Lv[8], l33 = Lv[9];
    float i0 = 1.f / l00, i1 = 1.f / l11, i2 = 1.f / l22, i3 = 1.f / l33;
    // W = inv(L), lower triangular (== forward-substitution coefficients)
    float w00 = i0;
    float w10 = -i1 * l10 * w00;
    float w11 = i1;
    float w20 = -i2 * (l20 * w00 + l21 * w10);
    float w21 = -i2 * (l21 * w11);
    float w22 = i2;
    float w30 = -i3 * (l30 * w00 + l31 * w10 + l32 * w20);
    float w31 = -i3 * (l31 * w11 + l32 * w21);
    float w32 = -i3 * (l32 * w22);
    float w33 = i3;
    float sl = __builtin_amdgcn_logf(fmaxf(fabsf(l00), 1e-8f)) +
               __builtin_amdgcn_logf(fmaxf(fabsf(l11), 1e-8f)) +
               __builtin_amdgcn_logf(fmaxf(fabsf(l22), 1e-8f)) +
               __builtin_amdgcn_logf(fmaxf(fabsf(l33), 1e-8f));
    float c2 = l2pi - C2CONST - sl;                   // log2-domain constant

    float4* P = reinterpret_cast<float4*>(ws) + tid * 4;
    P[0] = make_float4(muk[0], muk[1], muk[2], muk[3]);
    P[1] = make_float4(w00, w10, w11, w20);
    P[2] = make_float4(w21, w22, w30, w31);
    P[3] = make_float4(w32, w33, c2, 0.f);

    // z prefix columns
    float* zr = z + m * 80;
    #pragma unroll
    for (int d = 0; d < 4; ++d) zr[k * 4 + d] = muk[d];
    zr[32 + k * 4 + 0] = __builtin_amdgcn_logf(fmaxf(fabsf(l00), 1e-6f)) * LN2;
    zr[32 + k * 4 + 1] = __builtin_amdgcn_logf(fmaxf(fabsf(l11), 1e-6f)) * LN2;
    zr[32 + k * 4 + 2] = __builtin_amdgcn_logf(fmaxf(fabsf(l22), 1e-6f)) * LN2;
    zr[32 + k * 4 + 3] = __builtin_amdgcn_logf(fmaxf(fabsf(l33), 1e-6f)) * LN2;
    zr[64 + k] = pik;
}

// ---------------------------------------------------------------------------
// Kernel B: block-per-m. 512 blocks x 256 threads; each thread owns 16 of the
// 4096 points (4 chunks of 4, coalesced float4 loads). Params read at a
// blockIdx-uniform address (scalar broadcast; no LDS staging, no setup chain).
// Per-wave butterfly reduce + one LDS combine -> resp written directly to
// z[m*80+72..79] (B-scaled sums; column z-norm is scale-invariant). 2048
// waves total, 4x less per-wave overhead than R9's 8192.
// NOTE: per-point softmax MUST keep max-subtraction (R3 bug: collective exp2
// underflow zeroes responsibility mass).
// NOTE: no 2nd __launch_bounds__ arg (R4: treated as min-blocks/CU -> VGPR=64
// -> 458 MB/dispatch scratch spill).
// ---------------------------------------------------------------------------
__global__ __launch_bounds__(256) void gmm_main(const float* __restrict__ ws,
                                                const float* __restrict__ X,
                                                float* __restrict__ z) {
    __shared__ float swr[4][KK];
    const int m = blockIdx.x;
    const int t = threadIdx.x;
    const int w = t >> 6;
    const int lane = t & 63;

    const float4* Pm = reinterpret_cast<const float4*>(ws) + m * 32;  // uniform
    const float4* X4 = reinterpret_cast<const float4*>(X);

    float acc[KK];
    #pragma unroll
    for (int k = 0; k < KK; ++k) acc[k] = 0.f;

    #pragma unroll
    for (int c = 0; c < 4; ++c) {
        float4 xv[4];
        #pragma unroll
        for (int i = 0; i < 4; ++i) xv[i] = X4[c * 1024 + i * 256 + t];

        float lj[4][KK];
        #pragma unroll
        for (int k = 0; k < KK; ++k) {
            float4 p0 = Pm[k * 4 + 0], p1 = Pm[k * 4 + 1],
                   p2 = Pm[k * 4 + 2], p3 = Pm[k * 4 + 3];
            // mu=p0; w00,w10,w11,w20=p1; w21,w22,w30,w31=p2; w32,w33,c2=p3
            #pragma unroll
            for (int i = 0; i < 4; ++i) {
                float d0 = xv[i].x - p0.x;
                float d1 = xv[i].y - p0.y;
                float d2 = xv[i].z - p0.z;
                float d3 = xv[i].w - p0.w;
                float a0 = d0 * p1.x;
                float a1 = fmaf(p1.y, d0, d1 * p1.z);
                float a2 = fmaf(p1.w, d0, fmaf(p2.x, d1, d2 * p2.y));
                float a3 = fmaf(p2.z, d0, fmaf(p2.w, d1, fmaf(p3.x, d2, d3 * p3.y)));
                float sq = fmaf(a0, a0, fmaf(a1, a1, fmaf(a2, a2, a3 * a3)));
                lj[i][k] = fmaf(-HL2E, sq, p3.z);      // log2-domain
            }
        }
        #pragma unroll
        for (int i = 0; i < 4; ++i) {
            float mx = lj[i][0];
            #pragma unroll
            for (int k = 1; k < KK; ++k) mx = fmaxf(mx, lj[i][k]);
            float e[KK], s = 0.f;
            #pragma unroll
            for (int k = 0; k < KK; ++k) {
                e[k] = __builtin_amdgcn_exp2f(lj[i][k] - mx);  // bare v_exp_f32
                s += e[k];
            }
            float inv = __builtin_amdgcn_rcpf(s);      // s >= 1 (max term = 1)
            #pragma unroll
            for (int k = 0; k < KK; ++k) acc[k] = fmaf(e[k], inv, acc[k]);
        }
    }

    // per-wave butterfly; wave partials -> LDS; lanes 0-7 write resp to z
    #pragma unroll
    for (int k = 0; k < KK; ++k) {
        float v = acc[k];
        #pragma unroll
        for (int off = 32; off; off >>= 1) v += __shfl_xor(v, off, 64);
        acc[k] = v;
    }
    if (lane < KK) swr[w][lane] = acc[lane];
    __syncthreads();
    if (t < KK)
        z[m * 80 + 72 + t] = swr[0][t] + swr[1][t] + swr[2][t] + swr[3][t];
}

// ---------------------------------------------------------------------------
// Kernel C: column z-normalization (ddof=1), in place. 80 blocks x 512
// threads (one row each); every column is a plain coalesced z read now.
// ---------------------------------------------------------------------------
__global__ __launch_bounds__(512) void gmm_norm(float* __restrict__ z, int M) {
    __shared__ float sw[8];
    const int col = blockIdx.x;
    const int t = threadIdx.x;    // row m

    float v = z[t * 80 + col];

    float r = v;
    #pragma unroll
    for (int off = 32; off; off >>= 1) r += __shfl_xor(r, off, 64);
    if ((t & 63) == 0) sw[t >> 6] = r;
    __syncthreads();
    float tot = 0.f;
    #pragma unroll
    for (int w = 0; w < 8; ++w) tot += sw[w];
    float mean = tot / (float)M;
    __syncthreads();

    float d = v - mean;
    r = d * d;
    #pragma unroll
    for (int off = 32; off; off >>= 1) r += __shfl_xor(r, off, 64);
    if ((t & 63) == 0) sw[t >> 6] = r;
    __syncthreads();
    float tot2 = 0.f;
    #pragma unroll
    for (int w = 0; w < 8; ++w) tot2 += sw[w];
    float stdv = fmaxf(sqrtf(tot2 / (float)(M - 1)), 1e-6f);

    z[t * 80 + col] = d / stdv;
}

extern "C" void kernel_launch(void* const* d_in, const int* in_sizes, int n_in,
                              void* d_out, int out_size, void* d_ws, size_t ws_size,
                              hipStream_t stream) {
    const float* phi = (const float*)d_in[0];
    const float* X   = (const float*)d_in[1];
    const int M = in_sizes[0] / 120;  // 512
    float* ws = (float*)d_ws;         // params: M*K*16 floats
    float* z  = (float*)d_out;

    gmm_setup<<<(M * KK) / 256, 256, 0, stream>>>(phi, ws, z);
    gmm_main<<<M, 256, 0, stream>>>(ws, X, z);
    gmm_norm<<<80, 512, 0, stream>>>(z, M);
}